// Round 15
// baseline (205.435 us; speedup 1.0000x reference)
//
#include <hip/hip_runtime.h>
#include <hip/hip_bf16.h>
#include <math.h>

#define HH 128
#define WW 128
#define HW 16384
#define BB 2
#define CC 192

typedef __attribute__((ext_vector_type(8)))  short short8;
typedef __attribute__((ext_vector_type(4)))  float f32x4;
typedef __attribute__((ext_vector_type(16))) float f32x16;
typedef __attribute__((ext_vector_type(2)))  float f32x2;
typedef __attribute__((ext_vector_type(4)))  unsigned u32x4;

// f32 -> bf16 bits, round-to-nearest-even
static __device__ __forceinline__ short f2bf(float f) {
    unsigned u = __float_as_uint(f);
    unsigned r = (u + 0x7FFFu + ((u >> 16) & 1u)) >> 16;
    return (short)r;
}
// u32 of 2 bf16 -> f32x2 {lo, hi}
static __device__ __forceinline__ f32x2 unpk(unsigned u) {
    f32x2 r;
    r[0] = __uint_as_float(u << 16);
    r[1] = __uint_as_float(u & 0xFFFF0000u);
    return r;
}

// async global->LDS, 16B per lane (HW-verified width). dest: wave-uniform
// base + lane*16.
static __device__ __forceinline__ void gl_lds16(const void* gsrc, void* ldst) {
    __builtin_amdgcn_global_load_lds(
        (const __attribute__((address_space(1))) unsigned*)gsrc,
        (__attribute__((address_space(3))) unsigned*)ldst, 16, 0, 0);
}

// ---------------------------------------------------------------------------
// Grouped channels-last transpose: xg[b][cg(48)][pos][8ch] bf16.
// ---------------------------------------------------------------------------
__global__ __launch_bounds__(256) void to_grp_k(
    const float* __restrict__ xv, const float* __restrict__ xr,
    unsigned short* __restrict__ xg)
{
    const int idx = blockIdx.x * 256 + threadIdx.x;   // (b*48+cg)*HW + pos
    const int pos = idx & (HW - 1);
    const int cgb = idx >> 14;
    const int cg  = cgb % 48;
    const int b   = cgb / 48;
    short8 v;
#pragma unroll
    for (int r = 0; r < 8; r++) {
        const int c = cg * 8 + r;
        const float f = (c < 192)
            ? xv[((size_t)(b * 192 + c) << 14) + pos]
            : xr[((size_t)(b * 192 + (c - 192)) << 14) + pos];
        v[r] = f2bf(f);
    }
    *reinterpret_cast<short8*>(xg + (size_t)idx * 8) = v;
}

// ---------------------------------------------------------------------------
// Pack f32 weights into 32x32x16 A-frag chunks of 8 KB (round-14 form):
// wp[chunk*4096 + slot*512 + lane*8 + r], o = slot*32+(lane&31),
// k = chunk*16 + (lane>>5)*8 + r; src = w[o*so + (k/d1)*s1
//      + ((k%d1)/d2)*s2 + ((k%d1)%d2)*s3]. Zero-pad o >= Co.
// ---------------------------------------------------------------------------
__global__ void pack_w_k(const float* __restrict__ w, short* __restrict__ wp,
                         int Co, int so, int d1, int s1, int d2, int s2, int s3,
                         int total)
{
    const int idx = blockIdx.x * blockDim.x + threadIdx.x;
    if (idx >= total) return;
    const int lane  = idx & 63;
    const int slot  = (idx >> 6) & 7;
    const int chunk = idx >> 9;
    const int o     = slot * 32 + (lane & 31);
    const int k0    = chunk * 16 + ((lane >> 5) << 3);
    short8 v;
#pragma unroll
    for (int r = 0; r < 8; r++) {
        const int k = k0 + r;
        float f = 0.f;
        if (o < Co) {
            const int rem = k % d1;
            f = w[(size_t)o * so + (k / d1) * s1 + (rem / d2) * s2 + (rem % d2) * s3];
        }
        v[r] = f2bf(f);
    }
    *reinterpret_cast<short8*>(wp + (size_t)idx * 8) = v;
}

// ---------------------------------------------------------------------------
// 3x3 conv (pad 1), implicit GEMM, 32x32x16 MFMA, grouped-CL input.
// Round-14 skeleton (4 waves, 64 px, pair cadence, 3 A-buffers, 2 blocks/CU)
// with B register-loads replaced by an LDS B-tile [hi 2][3 rows][66 px][8ch]
// (6336 B) staged ONCE per c16 via gl_lds16 only, double-buffered; taps read
// it as conflict-free lane-consecutive ds_read_b128 + zero-mask.
// VMEM queue induction (in-order retirement):
//   prologue [A0(4), B0(2), A1(4)];
//   BODY(P): vmcnt(4) -> drains everything except newest 4 = A(P+1);
//   after barrier: issue B(c16+1)(2) iff t0 in {1,2} (once per c16), then
//   A(P+2)(4). Reads: Pbuf pair P (drained at this vmcnt), Btile (drained
//   >=2 bodies earlier, barrier-ordered). stageB write-after-read separated
//   by >=1 barrier from the last reader of the recycled buffer.
// LDS = 48K Pbuf + 16K Btile = 64K -> 2 blocks/CU preserved.
// ---------------------------------------------------------------------------
template<int MTW, int NC16, bool OUT_GRP>
__global__ __launch_bounds__(256, 2) void conv_g_k(
    const unsigned short* __restrict__ xg,
    const short* __restrict__ wA, const float* __restrict__ bias,
    void* __restrict__ outp, int Cout)
{
    __shared__ __align__(16) short Pbuf[3][2][4096];   // 48 KB
    __shared__ __align__(16) short Btile[2][4096];     // 16 KB (6336B used ea)

    const int t    = threadIdx.x;
    const int lane = t & 63;
    const int wid  = t >> 6;
    const int mg   = wid >> 1;
    const int nt   = wid & 1;
    // XCD swizzle: nwg = 2*HH*BB = 512
    const int lin  = (blockIdx.z * HH + blockIdx.y) * 2 + blockIdx.x;
    const int og_  = (lin & 7) * 64 + (lin >> 3);
    const int j0   = (og_ & 1) * 64;
    const int i    = (og_ >> 1) & (HH - 1);
    const int b    = og_ >> 8;
    const int pxw  = (nt << 5) + (lane & 31);          // 0..63
    const int hi   = lane >> 5;
    constexpr int NQ = NC16 * 9;
    constexpr int NP = NQ / 2;   // pairs (divisible by 3)

    const unsigned short* __restrict__ xgb = xg + (size_t)b * (NC16 * 2) * HW * 8;
    const char* __restrict__ xgc = (const char*)xgb;

    f32x16 acc[MTW];
#pragma unroll
    for (int m = 0; m < MTW; m++)
#pragma unroll
        for (int r = 0; r < 16; r++) acc[m][r] = 0.f;

    // ---- B-tile staging map: dest byte off = p*4096 + t*16; layout
    // run rn = hi*3+row (1056B each = 66px x 16B), rn<=5; junk (off>=6336)
    // clamps rn to 5 and lands in [6336,8192) slack, never read.
    int spat[2], hib[2];
#pragma unroll
    for (int p = 0; p < 2; p++) {
        const int off = p * 4096 + t * 16;
        int rn = off / 1056; rn = rn > 5 ? 5 : rn;
        const int wi  = off - rn * 1056;
        const int h_  = rn >= 3 ? 1 : 0;
        const int row = rn - 3 * h_;
        const int gy  = min(max(i - 1 + row, 0), HH - 1);
        spat[p] = ((gy << 7) + j0 - 1) * 16 + wi;      // may be -16 (guarded)
        hib[p]  = h_;
    }
    auto stageB = [&](int nb) {
        char* dstb = (char*)&Btile[nb & 1][0];
#pragma unroll
        for (int p = 0; p < 2; p++) {
            const char* src = xgc + (size_t)(nb * 2 + hib[p]) * (HW * 16) + spat[p];
            gl_lds16(src, dstb + p * 4096 + wid * 1024);
        }
    };
    auto stage2 = [&](int chunk, int pb, int sl) {
        gl_lds16(wA + (size_t)chunk * 4096 + t * 8,         &Pbuf[pb][sl][wid * 512]);
        gl_lds16(wA + (size_t)chunk * 4096 + (t + 256) * 8, &Pbuf[pb][sl][2048 + wid * 512]);
    };

    // prologue queue: A(p0)4, B(0)2, A(p1)4
    stage2(0, 0, 0); stage2(1, 0, 1);
    stageB(0);
    stage2(2, 1, 0); stage2(3, 1, 1);

#define CCHUNK(IBUF, SL, Q)                                                   \
    {                                                                         \
        const int cc16_ = (Q) / 9;                                            \
        const int tap_  = (Q) - 9 * cc16_;                                    \
        const int dy_ = tap_ / 3, dx_ = tap_ % 3;                             \
        const int iy_ = i + dy_ - 1;                                          \
        const int jx_ = j0 + pxw + dx_ - 1;                                   \
        short8 bF = *reinterpret_cast<const short8*>(                         \
            &Btile[cc16_ & 1][(hi * 3 + dy_) * 528 + (pxw + dx_) * 8]);       \
        if (!(((unsigned)iy_ < HH) && ((unsigned)jx_ < WW))) {                \
            _Pragma("unroll")                                                 \
            for (int r = 0; r < 8; r++) bF[r] = 0;                            \
        }                                                                     \
        const short* ab_ = &Pbuf[IBUF][SL][(mg * MTW) * 512 + lane * 8];      \
        short8 aF[MTW];                                                       \
        _Pragma("unroll")                                                     \
        for (int m = 0; m < MTW; m++)                                         \
            aF[m] = *reinterpret_cast<const short8*>(ab_ + m * 512);          \
        __builtin_amdgcn_s_setprio(1);                                        \
        _Pragma("unroll")                                                     \
        for (int m = 0; m < MTW; m++)                                         \
            acc[m] = __builtin_amdgcn_mfma_f32_32x32x16_bf16(aF[m], bF, acc[m], 0, 0, 0); \
        __builtin_amdgcn_s_setprio(0);                                        \
    }

#define PSTEP(P, IBUF, SBUF)                                                  \
    {                                                                         \
        asm volatile("s_waitcnt vmcnt(4)" ::: "memory");                      \
        __builtin_amdgcn_s_barrier();                                         \
        __builtin_amdgcn_sched_barrier(0);                                    \
        const int q0_  = 2 * (P);                                             \
        const int c16_ = q0_ / 9;                                             \
        const int t0_  = q0_ - 9 * c16_;                                      \
        if (t0_ == 1 || t0_ == 2) stageB(min(c16_ + 1, NC16 - 1));            \
        stage2(min(2 * ((P) + 2),     NQ - 1), SBUF, 0);                      \
        stage2(min(2 * ((P) + 2) + 1, NQ - 1), SBUF, 1);                      \
        CCHUNK(IBUF, 0, q0_);                                                 \
        CCHUNK(IBUF, 1, q0_ + 1);                                             \
    }

    for (int pp = 0; pp < NP; pp += 3) {
        PSTEP(pp + 0, 0, 2);
        PSTEP(pp + 1, 1, 0);
        PSTEP(pp + 2, 2, 1);
    }
#undef PSTEP
#undef CCHUNK

    // store. C/D: col = lane&31 -> px ; row = (reg&3)+8*(reg>>2)+4*hi -> o.
    const int pos_o = (i << 7) + j0 + pxw;
    if constexpr (OUT_GRP) {
        unsigned short* fg = (unsigned short*)outp;
#pragma unroll
        for (int m = 0; m < MTW; m++) {
            const int mt32 = mg * MTW + m;
#pragma unroll
            for (int g = 0; g < 4; g++) {
                const int ob = mt32 * 32 + 8 * g + 4 * hi;
                const unsigned s0 = (unsigned short)f2bf(acc[m][4 * g + 0] + bias[ob + 0]);
                const unsigned s1 = (unsigned short)f2bf(acc[m][4 * g + 1] + bias[ob + 1]);
                const unsigned s2 = (unsigned short)f2bf(acc[m][4 * g + 2] + bias[ob + 2]);
                const unsigned s3 = (unsigned short)f2bf(acc[m][4 * g + 3] + bias[ob + 3]);
                const int cg = mt32 * 4 + g;
                *reinterpret_cast<uint2*>(
                    fg + ((size_t)(b * (Cout >> 3) + cg) * HW + pos_o) * 8 + 4 * hi) =
                    make_uint2(s0 | (s1 << 16), s2 | (s3 << 16));
            }
        }
    } else {
        float* of = (float*)outp;
#pragma unroll
        for (int m = 0; m < MTW; m++) {
            const int mt32 = mg * MTW + m;
#pragma unroll
            for (int reg = 0; reg < 16; reg++) {
                const int o = mt32 * 32 + (reg & 3) + ((reg >> 2) << 3) + (hi << 2);
                if (o < Cout)
                    of[((size_t)(b * Cout + o) << 14) + pos_o] = acc[m][reg] + bias[o];
            }
        }
    }
}

// ---------------------------------------------------------------------------
// Fused deform-sample + einsum, 32x32x16 MFMA, producer-split bF sharing.
// (Round-14 verbatim — passing at 174 us.) Block = 128 thr (2 waves),
// 32 px x 192 out-ch; grid 1024 -> 4 blocks/CU. Per pair per wave issue:
// 4 G + 6 A -> exact vmcnt(10).
// ---------------------------------------------------------------------------
__global__ __launch_bounds__(128, 2) void dcn_g_k(
    const unsigned short* __restrict__ xg, const float* __restrict__ off,
    const short* __restrict__ wA, const float* __restrict__ bias,
    float* __restrict__ out)
{
    __shared__ __align__(16) f32x4 eW[1152];      // 18.4 KB (36 gk x 32 px)
    __shared__ __align__(8)  uint2 eO[1152];      //  9.2 KB
    __shared__ __align__(16) short bfS[2][2][512];//  4 KB  [buf][subchunk][.]

    const int t    = threadIdx.x;
    const int lane = t & 63;
    const int w    = t >> 6;     // wave id = producer sub-chunk = m-half
    // XCD swizzle: nwg = 4*HH*BB = 1024
    const int lin  = (blockIdx.z * HH + blockIdx.y) * 4 + blockIdx.x;
    const int og_  = (lin & 7) * 128 + (lin >> 3);
    const int jt   = og_ & 3;
    const int i    = (og_ >> 2) & (HH - 1);
    const int b    = og_ >> 9;
    const int j0   = jt * 32;

    // ---- A1: bilinear entries (identical math to verified rounds 2-14) ----
    for (int e = t; e < 1152; e += 128) {
        const int p  = e & 31;
        const int gk = e >> 5;               // g*9 + kt
        const int kt = gk % 9;
        const int j  = j0 + p;
        const size_t sp = (size_t)b * 108 * HW + (size_t)gk * HW + (i << 7) + j;
        const float dy = off[sp];
        const float dx = off[sp + (size_t)36 * HW];
        const float mv = off[sp + (size_t)72 * HW];
        const float m  = 1.f / (1.f + expf(-mv));
        const float py = (float)(i + kt / 3 - 1) + dy;
        const float px = (float)(j + kt % 3 - 1) + dx;
        const float y0f = floorf(py), x0f = floorf(px);
        const float ly = py - y0f, lx = px - x0f;
        const int y0 = (int)y0f, x0 = (int)x0f;
        const float vy0 = (y0 >= 0 && y0 < HH) ? 1.f : 0.f;
        const float vy1 = (y0 + 1 >= 0 && y0 + 1 < HH) ? 1.f : 0.f;
        const float vx0 = (x0 >= 0 && x0 < WW) ? 1.f : 0.f;
        const float vx1 = (x0 + 1 >= 0 && x0 + 1 < WW) ? 1.f : 0.f;
        f32x4 w4;
        w4[0] = (1.f - ly) * (1.f - lx) * m * vy0 * vx0;
        w4[1] = (1.f - ly) * lx         * m * vy0 * vx1;
        w4[2] = ly         * (1.f - lx) * m * vy1 * vx0;
        w4[3] = ly         * lx         * m * vy1 * vx1;
        const int yc0 = min(max(y0, 0), HH - 1);
        const int yc1 = min(max(y0 + 1, 0), HH - 1);
        const int xc0 = min(max(x0, 0), WW - 1);
        const int xc1 = min(max(x0 + 1, 0), WW - 1);
        eW[e] = w4;
        eO[e] = make_uint2((unsigned)((yc0 << 7) + xc0) | ((unsigned)((yc0 << 7) + xc1) << 16),
                           (unsigned)((yc1 << 7) + xc0) | ((unsigned)((yc1 << 7) + xc1) << 16));
    }
    __syncthreads();

    const int px_l = lane & 31;
    const int hi   = lane >> 5;
    const unsigned short* __restrict__ xgb = xg + (size_t)b * 48 * HW * 8;

    f32x16 acc[3];
#pragma unroll
    for (int m = 0; m < 3; m++)
#pragma unroll
        for (int r = 0; r < 16; r++) acc[m][r] = 0.f;

    // my gather chunk for pair P is 2P + w
#define GISSUE(QQ, N0, N1, N2, N3, WN)                                        \
    {                                                                         \
        const int qn_   = min((QQ), 107);                                     \
        const int c16n_ = qn_ / 9;                                            \
        const int ktn_  = qn_ - 9 * c16n_;                                    \
        const int e_    = ((c16n_ / 3) * 9 + ktn_) * 32 + px_l;               \
        const uint2 o_  = eO[e_];                                             \
        WN = eW[e_];                                                          \
        const unsigned short* base_ = xgb + (size_t)(c16n_ * 2 + hi) * (HW * 8); \
        N0 = *reinterpret_cast<const u32x4*>(base_ + (size_t)(o_.x & 0xFFFFu) * 8); \
        N1 = *reinterpret_cast<const u32x4*>(base_ + (size_t)(o_.x >> 16) * 8);     \
        N2 = *reinterpret_cast<const u32x4*>(base_ + (size_t)(o_.y & 0xFFFFu) * 8); \
        N3 = *reinterpret_cast<const u32x4*>(base_ + (size_t)(o_.y >> 16) * 8);     \
    }

    // A frags for pair P (chunks 2P, 2P+1), m-half w: 6 b128 loads
#define AISSUE(PP, DST)                                                       \
    {                                                                         \
        const short* a0_ = wA + (size_t)min(2 * (PP),     107) * 4096 + (w * 3) * 512 + lane * 8; \
        const short* a1_ = wA + (size_t)min(2 * (PP) + 1, 107) * 4096 + (w * 3) * 512 + lane * 8; \
        DST[0] = *reinterpret_cast<const short8*>(a0_);                       \
        DST[1] = *reinterpret_cast<const short8*>(a0_ + 512);                 \
        DST[2] = *reinterpret_cast<const short8*>(a0_ + 1024);                \
        DST[3] = *reinterpret_cast<const short8*>(a1_);                       \
        DST[4] = *reinterpret_cast<const short8*>(a1_ + 512);                 \
        DST[5] = *reinterpret_cast<const short8*>(a1_ + 1024);                \
    }

#define PAIRSTEP(P, Ac, C0, C1, C2, C3, WC, An, N0, N1, N2, N3, WN)           \
    {                                                                         \
        GISSUE(2 * ((P) + 1) + w, N0, N1, N2, N3, WN);                        \
        AISSUE((P) + 1, An);                                                  \
        asm volatile("s_waitcnt vmcnt(10)" ::: "memory");                     \
        u32x4 rv_;                                                            \
        _Pragma("unroll")                                                     \
        for (int jj = 0; jj < 4; jj++) {                                      \
            f32x2 v_ = WC[0] * unpk(C0[jj]) + WC[1] * unpk(C1[jj])            \
                     + WC[2] * unpk(C2[jj]) + WC[3] * unpk(C3[jj]);           \
            __hip_bfloat162 h2_ = __float22bfloat162_rn(make_float2(v_[0], v_[1])); \
            unsigned hu_; __builtin_memcpy(&hu_, &h2_, 4);                    \
            rv_[jj] = hu_;                                                    \
        }                                                                     \
        *reinterpret_cast<u32x4*>(&bfS[(P) & 1][w][lane * 8]) = rv_;          \
        asm volatile("s_waitcnt lgkmcnt(0)" ::: "memory");                    \
        __builtin_amdgcn_s_barrier();                                         \
        __builtin_amdgcn_sched_barrier(0);                                    \
        const short8 bf0_ = *reinterpret_cast<const short8*>(&bfS[(P) & 1][0][lane * 8]); \
        const short8 bf1_ = *reinterpret_cast<const short8*>(&bfS[(P) & 1][1][lane * 8]); \
        __builtin_amdgcn_s_setprio(1);                                        \
        acc[0] = __builtin_amdgcn_mfma_f32_32x32x16_bf16(Ac[0], bf0_, acc[0], 0, 0, 0); \
        acc[1] = __builtin_amdgcn_mfma_f32_32x32x16_bf16(Ac[1], bf0_, acc[1], 0, 0, 0); \
        acc[2] = __builtin_amdgcn_mfma_f32_32x32x16_bf16(Ac[2], bf0_, acc[2], 0, 0, 0); \
        acc[0] = __builtin_amdgcn_mfma_f32_32x32x16_bf16(Ac[3], bf1_, acc[0], 0, 0, 0); \
        acc[1] = __builtin_amdgcn_mfma_f32_32x32x16_bf16(Ac[4], bf1_, acc[1], 0, 0, 0); \
        acc[2] = __builtin_amdgcn_mfma_f32_32x32x16_bf16(Ac[5], bf1_, acc[2], 0, 0, 0); \
        __builtin_amdgcn_s_setprio(0);                                        \
    }

    short8 Aa[6], Ab[6];
    u32x4 Gx0, Gx1, Gx2, Gx3, Gy0, Gy1, Gy2, Gy3;
    f32x4 wGx, wGy;

    // prologue: pair 0's G (4) + A (6) -> 10 outstanding
    GISSUE(0 + w, Gx0, Gx1, Gx2, Gx3, wGx);
    AISSUE(0, Aa);

    for (int pr = 0; pr < 54; pr += 2) {
        PAIRSTEP(pr,     Aa, Gx0, Gx1, Gx2, Gx3, wGx, Ab, Gy0, Gy1, Gy2, Gy3, wGy);
        PAIRSTEP(pr + 1, Ab, Gy0, Gy1, Gy2, Gy3, wGy, Aa, Gx0, Gx1, Gx2, Gx3, wGx);
    }
#undef PAIRSTEP
#undef AISSUE
#undef GISSUE

    const int pos_o = (i << 7) + j0 + px_l;
#pragma unroll
    for (int m = 0; m < 3; m++) {
        const int mt32 = w * 3 + m;
#pragma unroll
        for (int reg = 0; reg < 16; reg++) {
            const int o = mt32 * 32 + (reg & 3) + ((reg >> 2) << 3) + (hi << 2);
            out[((size_t)(b * CC + o) << 14) + pos_o] = acc[m][reg] + bias[o];
        }
    }
}

// ---------------------------------------------------------------------------
extern "C" void kernel_launch(void* const* d_in, const int* in_sizes, int n_in,
                              void* d_out, int out_size, void* d_ws, size_t ws_size,
                              hipStream_t stream)
{
    const float* x_vq  = (const float*)d_in[0];
    const float* x_res = (const float*)d_in[1];
    const float* w_off = (const float*)d_in[2];
    const float* b_off = (const float*)d_in[3];
    const float* w_co  = (const float*)d_in[4];
    const float* b_co  = (const float*)d_in[5];
    const float* w_dcn = (const float*)d_in[6];
    const float* b_dcn = (const float*)d_in[7];
    float* out = (float*)d_out;

    char* ws = (char*)d_ws;
    unsigned short* xg = (unsigned short*)(ws + 256);              // +256 guard
    const size_t xg_sz = (size_t)BB * 48 * HW * 8 * 2;
    unsigned short* fg = (unsigned short*)(ws + 256 + xg_sz);      // 12.58 MB
    const size_t fg_sz = (size_t)BB * 24 * HW * 8 * 2;
    float* offb = (float*)(ws + 256 + xg_sz + fg_sz);              // 14.16 MB
    const size_t offb_sz = (size_t)BB * 108 * HW * 4;
    short* wA1 = (short*)(ws + 256 + xg_sz + fg_sz + offb_sz);     // 216*4096
    short* wA2 = wA1 + (size_t)216 * 4096;                         // 108*4096
    short* wA3 = wA2 + (size_t)108 * 4096;                         // 108*4096

    to_grp_k<<<dim3(BB * 48 * HW / 256), 256, 0, stream>>>(x_vq, x_res, xg);

    // packing. conv: k = c16*144 + tap*16 + cl -> w[o][c16*16+cl][tap]
    pack_w_k<<<(216 * 512 + 255) / 256, 256, 0, stream>>>(
        w_off, wA1, 192, 3456, 144, 144, 16, 1, 9, 216 * 512);
    pack_w_k<<<(108 * 512 + 255) / 256, 256, 0, stream>>>(
        w_co, wA2, 108, 1728, 144, 144, 16, 1, 9, 108 * 512);
    // dcn (c16-outer order): k = c16*144 + kt*16 + cl -> w[o][c16*16+cl][kt]
    pack_w_k<<<(108 * 512 + 255) / 256, 256, 0, stream>>>(
        w_dcn, wA3, 192, 1728, 144, 144, 16, 1, 9, 108 * 512);

    // conv1: xg [48 grp] -> fg [24 grp bf16]
    conv_g_k<3, 24, true><<<dim3(2, HH, BB), 256, 0, stream>>>(xg, wA1, b_off, fg, 192);
    // conv2: fg [24 grp] -> offb [108 planar f32]
    conv_g_k<2, 12, false><<<dim3(2, HH, BB), 256, 0, stream>>>(fg, wA2, b_co, offb, 108);
    // fused deform-sample + einsum (producer-split, round-14 verbatim)
    dcn_g_k<<<dim3(4, HH, BB), 128, 0, stream>>>(xg, offb, wA3, b_dcn, out);
}

// Round 16
// 176.178 us; speedup vs baseline: 1.1661x; 1.1661x over previous
//
#include <hip/hip_runtime.h>
#include <hip/hip_bf16.h>
#include <math.h>

#define HH 128
#define WW 128
#define HW 16384
#define BB 2
#define CC 192

typedef __attribute__((ext_vector_type(8)))  short short8;
typedef __attribute__((ext_vector_type(4)))  float f32x4;
typedef __attribute__((ext_vector_type(16))) float f32x16;
typedef __attribute__((ext_vector_type(2)))  float f32x2;
typedef __attribute__((ext_vector_type(4)))  unsigned u32x4;

// f32 -> bf16 bits, round-to-nearest-even
static __device__ __forceinline__ short f2bf(float f) {
    unsigned u = __float_as_uint(f);
    unsigned r = (u + 0x7FFFu + ((u >> 16) & 1u)) >> 16;
    return (short)r;
}
// u32 of 2 bf16 -> f32x2 {lo, hi}
static __device__ __forceinline__ f32x2 unpk(unsigned u) {
    f32x2 r;
    r[0] = __uint_as_float(u << 16);
    r[1] = __uint_as_float(u & 0xFFFF0000u);
    return r;
}

// async global->LDS, 16B per lane (HW-verified width). dest: wave-uniform
// base + lane*16.
static __device__ __forceinline__ void gl_lds16(const void* gsrc, void* ldst) {
    __builtin_amdgcn_global_load_lds(
        (const __attribute__((address_space(1))) unsigned*)gsrc,
        (__attribute__((address_space(3))) unsigned*)ldst, 16, 0, 0);
}

// ---------------------------------------------------------------------------
// Grouped channels-last transpose: xg[b][cg(48)][pos][8ch] bf16.
// ---------------------------------------------------------------------------
__global__ __launch_bounds__(256) void to_grp_k(
    const float* __restrict__ xv, const float* __restrict__ xr,
    unsigned short* __restrict__ xg)
{
    const int idx = blockIdx.x * 256 + threadIdx.x;   // (b*48+cg)*HW + pos
    const int pos = idx & (HW - 1);
    const int cgb = idx >> 14;
    const int cg  = cgb % 48;
    const int b   = cgb / 48;
    short8 v;
#pragma unroll
    for (int r = 0; r < 8; r++) {
        const int c = cg * 8 + r;
        const float f = (c < 192)
            ? xv[((size_t)(b * 192 + c) << 14) + pos]
            : xr[((size_t)(b * 192 + (c - 192)) << 14) + pos];
        v[r] = f2bf(f);
    }
    *reinterpret_cast<short8*>(xg + (size_t)idx * 8) = v;
}

// ---------------------------------------------------------------------------
// Pack f32 weights into 32x32x16 A-frag chunks of SLOTS KB:
// wp[(chunk*SLOTS + slot)*512 + lane*8 + r], o = slot*32+(lane&31),
// k = chunk*16 + (lane>>5)*8 + r; src = w[o*so + (k/d1)*s1
//      + ((k%d1)/d2)*s2 + ((k%d1)%d2)*s3]. Zero-pad o >= Co.
// ---------------------------------------------------------------------------
__global__ void pack_w_k(const float* __restrict__ w, short* __restrict__ wp,
                         int Co, int so, int d1, int s1, int d2, int s2, int s3,
                         int SLOTS, int total)
{
    const int idx = blockIdx.x * blockDim.x + threadIdx.x;
    if (idx >= total) return;
    const int lane  = idx & 63;
    const int slot  = (idx >> 6) % SLOTS;
    const int chunk = (idx >> 6) / SLOTS;
    const int o     = slot * 32 + (lane & 31);
    const int k0    = chunk * 16 + ((lane >> 5) << 3);
    short8 v;
#pragma unroll
    for (int r = 0; r < 8; r++) {
        const int k = k0 + r;
        float f = 0.f;
        if (o < Co) {
            const int rem = k % d1;
            f = w[(size_t)o * so + (k / d1) * s1 + (rem / d2) * s2 + (rem % d2) * s3];
        }
        v[r] = f2bf(f);
    }
    *reinterpret_cast<short8*>(wp + (size_t)idx * 8) = v;
}

// ---------------------------------------------------------------------------
// 3x3 conv (pad 1), implicit GEMM, 32x32x16 MFMA, grouped-CL input.
// M-SPLIT blocks: 128 thr (2 waves = px halves nt), MTW m-tiles of the
// chalf half of Cout, 64 px; grid 1024 -> 4 independent blocks/CU (vs
// round-14's 2) — per-CU VMEM instr & bytes identical to round 14
// (B 16KB, A 16KB, 48 VMEM instr per pair-time), pure desync/occupancy win.
// Pair cadence + 3 A-buffer rotation as round 14. A chunks: SLOTS=2*MTW
// 1KB slots; block stages its chalf's MTW KB in NPASS gl_lds16 passes
// (conv1: 3KB in 2x2KB passes, 1KB overrun lands in slot slack / +1KB pad
// at wA end; conv2: 2KB in 1 pass exact).
// VMEM queue induction (in-order): steady state at vmcnt =
// [B(P+1) 2, S(P+1) 2*NPASS, B(P+2) 2] -> vmcnt(4+2*NPASS) = 8 / 6;
// drains S(P), B(P) exactly.
// ---------------------------------------------------------------------------
template<int MTW, int NC16, bool OUT_GRP>
__global__ __launch_bounds__(128, 2) void conv_g_k(
    const unsigned short* __restrict__ xg,
    const short* __restrict__ wA, const float* __restrict__ bias,
    void* __restrict__ outp, int Cout)
{
    constexpr int NPASS   = (MTW >= 3) ? 2 : 1;
    constexpr int SLOT_SH = NPASS * 1024;          // shorts per chunk-slot
    __shared__ __align__(16) short Pbuf[3][2][SLOT_SH];

    const int t    = threadIdx.x;
    const int lane = t & 63;
    const int wid  = t >> 6;          // wave id = px half (nt)
    // XCD swizzle: nwg = 4*HH*BB = 1024; chalf = og_&1 -> both chalf blocks
    // of a px-range land on the same XCD (B reuse in its L2).
    const int lin   = (blockIdx.z * HH + blockIdx.y) * 4 + blockIdx.x;
    const int og_   = (lin & 7) * 128 + (lin >> 3);
    const int chalf = og_ & 1;
    const int pxh   = (og_ >> 1) & 1;
    const int i     = (og_ >> 2) & (HH - 1);
    const int b     = og_ >> 9;
    const int px    = pxh * 64 + (wid << 5) + (lane & 31);
    const int hi    = lane >> 5;
    constexpr int NQ = NC16 * 9;
    constexpr int NP = NQ / 2;        // pairs (divisible by 3)

    const unsigned short* __restrict__ xgb = xg + (size_t)b * (NC16 * 2) * HW * 8;

    f32x16 acc[MTW];
#pragma unroll
    for (int m = 0; m < MTW; m++)
#pragma unroll
        for (int r = 0; r < 16; r++) acc[m][r] = 0.f;

    auto loadB = [&](int qq, short8& dst, bool& vm) {
        const int c16 = qq / 9;
        const int tap = qq - c16 * 9;
        const int iy  = i + tap / 3 - 1;
        const int jx  = px + tap % 3 - 1;
        vm = ((unsigned)iy < HH) && ((unsigned)jx < WW);
        const int iyc = min(max(iy, 0), HH - 1);
        const int jxc = min(max(jx, 0), WW - 1);
        dst = *reinterpret_cast<const short8*>(
            xgb + ((size_t)(c16 * 2 + hi) * HW + (iyc << 7) + jxc) * 8);
    };
    // stage this chalf's MTW KB of chunk into Pbuf[pb][sl]
    auto stageA = [&](int chunk, int pb, int sl) {
        const short* src = wA + (size_t)chunk * (2 * MTW * 512) + chalf * (MTW * 512);
#pragma unroll
        for (int p = 0; p < NPASS; p++)
            gl_lds16(src + p * 1024 + t * 8, &Pbuf[pb][sl][p * 1024 + wid * 512]);
    };

    short8 B0, B1, B2, B3, B4, B5;
    bool M0, M1, M2, M3, M4, M5;

    // prologue (queue invariant): S(p0), B(p0), S(p1), B(p1)
    stageA(0, 0, 0); stageA(1, 0, 1);
    loadB(0, B0, M0); loadB(1, B1, M1);
    stageA(2, 1, 0); stageA(3, 1, 1);
    loadB(2, B2, M2); loadB(3, B3, M3);

#define CCHUNK(IBUF, SL, BC, MC)                                              \
    {                                                                         \
        short8 bF = BC;                                                       \
        if (!MC) {                                                            \
            _Pragma("unroll")                                                 \
            for (int r = 0; r < 8; r++) bF[r] = 0;                            \
        }                                                                     \
        const short* ab_ = &Pbuf[IBUF][SL][lane * 8];                         \
        short8 aF[MTW];                                                       \
        _Pragma("unroll")                                                     \
        for (int m = 0; m < MTW; m++)                                         \
            aF[m] = *reinterpret_cast<const short8*>(ab_ + m * 512);          \
        __builtin_amdgcn_s_setprio(1);                                        \
        _Pragma("unroll")                                                     \
        for (int m = 0; m < MTW; m++)                                         \
            acc[m] = __builtin_amdgcn_mfma_f32_32x32x16_bf16(aF[m], bF, acc[m], 0, 0, 0); \
        __builtin_amdgcn_s_setprio(0);                                        \
    }

#define PSTEP(P, IBUF, SBUF, Bc0, Mc0, Bc1, Mc1, Bn0, Mn0, Bn1, Mn1)          \
    {                                                                         \
        loadB(min(2 * ((P) + 2),     NQ - 1), Bn0, Mn0);                      \
        loadB(min(2 * ((P) + 2) + 1, NQ - 1), Bn1, Mn1);                      \
        if constexpr (NPASS == 2) {                                           \
            asm volatile("s_waitcnt vmcnt(8)" ::: "memory");                  \
        } else {                                                              \
            asm volatile("s_waitcnt vmcnt(6)" ::: "memory");                  \
        }                                                                     \
        __builtin_amdgcn_s_barrier();                                         \
        __builtin_amdgcn_sched_barrier(0);                                    \
        stageA(min(2 * ((P) + 2),     NQ - 1), SBUF, 0);                      \
        stageA(min(2 * ((P) + 2) + 1, NQ - 1), SBUF, 1);                      \
        CCHUNK(IBUF, 0, Bc0, Mc0);                                            \
        CCHUNK(IBUF, 1, Bc1, Mc1);                                            \
    }

    for (int pp = 0; pp < NP; pp += 3) {
        PSTEP(pp + 0, 0, 2, B0, M0, B1, M1, B4, M4, B5, M5);
        PSTEP(pp + 1, 1, 0, B2, M2, B3, M3, B0, M0, B1, M1);
        PSTEP(pp + 2, 2, 1, B4, M4, B5, M5, B2, M2, B3, M3);
    }
#undef PSTEP
#undef CCHUNK

    // store. C/D: col = lane&31 -> px ; row = (reg&3)+8*(reg>>2)+4*hi -> o.
    const int pos_o = (i << 7) + px;
    if constexpr (OUT_GRP) {
        unsigned short* fg = (unsigned short*)outp;
#pragma unroll
        for (int m = 0; m < MTW; m++) {
            const int mt32 = chalf * MTW + m;
#pragma unroll
            for (int g = 0; g < 4; g++) {
                const int ob = mt32 * 32 + 8 * g + 4 * hi;
                const unsigned s0 = (unsigned short)f2bf(acc[m][4 * g + 0] + bias[ob + 0]);
                const unsigned s1 = (unsigned short)f2bf(acc[m][4 * g + 1] + bias[ob + 1]);
                const unsigned s2 = (unsigned short)f2bf(acc[m][4 * g + 2] + bias[ob + 2]);
                const unsigned s3 = (unsigned short)f2bf(acc[m][4 * g + 3] + bias[ob + 3]);
                const int cg = mt32 * 4 + g;
                *reinterpret_cast<uint2*>(
                    fg + ((size_t)(b * (Cout >> 3) + cg) * HW + pos_o) * 8 + 4 * hi) =
                    make_uint2(s0 | (s1 << 16), s2 | (s3 << 16));
            }
        }
    } else {
        float* of = (float*)outp;
#pragma unroll
        for (int m = 0; m < MTW; m++) {
            const int mt32 = chalf * MTW + m;
#pragma unroll
            for (int reg = 0; reg < 16; reg++) {
                const int o = mt32 * 32 + (reg & 3) + ((reg >> 2) << 3) + (hi << 2);
                if (o < Cout)
                    of[((size_t)(b * Cout + o) << 14) + pos_o] = acc[m][reg] + bias[o];
            }
        }
    }
}

// ---------------------------------------------------------------------------
// Fused deform-sample + einsum, 32x32x16 MFMA, producer-split bF sharing.
// (Round-14 verbatim — passing at 174 us.) Block = 128 thr (2 waves),
// 32 px x 192 out-ch; grid 1024 -> 4 blocks/CU. Per pair per wave issue:
// 4 G + 6 A -> exact vmcnt(10).
// ---------------------------------------------------------------------------
__global__ __launch_bounds__(128, 2) void dcn_g_k(
    const unsigned short* __restrict__ xg, const float* __restrict__ off,
    const short* __restrict__ wA, const float* __restrict__ bias,
    float* __restrict__ out)
{
    __shared__ __align__(16) f32x4 eW[1152];      // 18.4 KB (36 gk x 32 px)
    __shared__ __align__(8)  uint2 eO[1152];      //  9.2 KB
    __shared__ __align__(16) short bfS[2][2][512];//  4 KB  [buf][subchunk][.]

    const int t    = threadIdx.x;
    const int lane = t & 63;
    const int w    = t >> 6;     // wave id = producer sub-chunk = m-half
    // XCD swizzle: nwg = 4*HH*BB = 1024
    const int lin  = (blockIdx.z * HH + blockIdx.y) * 4 + blockIdx.x;
    const int og_  = (lin & 7) * 128 + (lin >> 3);
    const int jt   = og_ & 3;
    const int i    = (og_ >> 2) & (HH - 1);
    const int b    = og_ >> 9;
    const int j0   = jt * 32;

    // ---- A1: bilinear entries (identical math to verified rounds 2-14) ----
    for (int e = t; e < 1152; e += 128) {
        const int p  = e & 31;
        const int gk = e >> 5;               // g*9 + kt
        const int kt = gk % 9;
        const int j  = j0 + p;
        const size_t sp = (size_t)b * 108 * HW + (size_t)gk * HW + (i << 7) + j;
        const float dy = off[sp];
        const float dx = off[sp + (size_t)36 * HW];
        const float mv = off[sp + (size_t)72 * HW];
        const float m  = 1.f / (1.f + expf(-mv));
        const float py = (float)(i + kt / 3 - 1) + dy;
        const float px = (float)(j + kt % 3 - 1) + dx;
        const float y0f = floorf(py), x0f = floorf(px);
        const float ly = py - y0f, lx = px - x0f;
        const int y0 = (int)y0f, x0 = (int)x0f;
        const float vy0 = (y0 >= 0 && y0 < HH) ? 1.f : 0.f;
        const float vy1 = (y0 + 1 >= 0 && y0 + 1 < HH) ? 1.f : 0.f;
        const float vx0 = (x0 >= 0 && x0 < WW) ? 1.f : 0.f;
        const float vx1 = (x0 + 1 >= 0 && x0 + 1 < WW) ? 1.f : 0.f;
        f32x4 w4;
        w4[0] = (1.f - ly) * (1.f - lx) * m * vy0 * vx0;
        w4[1] = (1.f - ly) * lx         * m * vy0 * vx1;
        w4[2] = ly         * (1.f - lx) * m * vy1 * vx0;
        w4[3] = ly         * lx         * m * vy1 * vx1;
        const int yc0 = min(max(y0, 0), HH - 1);
        const int yc1 = min(max(y0 + 1, 0), HH - 1);
        const int xc0 = min(max(x0, 0), WW - 1);
        const int xc1 = min(max(x0 + 1, 0), WW - 1);
        eW[e] = w4;
        eO[e] = make_uint2((unsigned)((yc0 << 7) + xc0) | ((unsigned)((yc0 << 7) + xc1) << 16),
                           (unsigned)((yc1 << 7) + xc0) | ((unsigned)((yc1 << 7) + xc1) << 16));
    }
    __syncthreads();

    const int px_l = lane & 31;
    const int hi   = lane >> 5;
    const unsigned short* __restrict__ xgb = xg + (size_t)b * 48 * HW * 8;

    f32x16 acc[3];
#pragma unroll
    for (int m = 0; m < 3; m++)
#pragma unroll
        for (int r = 0; r < 16; r++) acc[m][r] = 0.f;

    // my gather chunk for pair P is 2P + w
#define GISSUE(QQ, N0, N1, N2, N3, WN)                                        \
    {                                                                         \
        const int qn_   = min((QQ), 107);                                     \
        const int c16n_ = qn_ / 9;                                            \
        const int ktn_  = qn_ - 9 * c16n_;                                    \
        const int e_    = ((c16n_ / 3) * 9 + ktn_) * 32 + px_l;               \
        const uint2 o_  = eO[e_];                                             \
        WN = eW[e_];                                                          \
        const unsigned short* base_ = xgb + (size_t)(c16n_ * 2 + hi) * (HW * 8); \
        N0 = *reinterpret_cast<const u32x4*>(base_ + (size_t)(o_.x & 0xFFFFu) * 8); \
        N1 = *reinterpret_cast<const u32x4*>(base_ + (size_t)(o_.x >> 16) * 8);     \
        N2 = *reinterpret_cast<const u32x4*>(base_ + (size_t)(o_.y & 0xFFFFu) * 8); \
        N3 = *reinterpret_cast<const u32x4*>(base_ + (size_t)(o_.y >> 16) * 8);     \
    }

    // A frags for pair P (chunks 2P, 2P+1), m-half w: 6 b128 loads
#define AISSUE(PP, DST)                                                       \
    {                                                                         \
        const short* a0_ = wA + (size_t)min(2 * (PP),     107) * 4096 + (w * 3) * 512 + lane * 8; \
        const short* a1_ = wA + (size_t)min(2 * (PP) + 1, 107) * 4096 + (w * 3) * 512 + lane * 8; \
        DST[0] = *reinterpret_cast<const short8*>(a0_);                       \
        DST[1] = *reinterpret_cast<const short8*>(a0_ + 512);                 \
        DST[2] = *reinterpret_cast<const short8*>(a0_ + 1024);                \
        DST[3] = *reinterpret_cast<const short8*>(a1_);                       \
        DST[4] = *reinterpret_cast<const short8*>(a1_ + 512);                 \
        DST[5] = *reinterpret_cast<const short8*>(a1_ + 1024);                \
    }

#define PAIRSTEP(P, Ac, C0, C1, C2, C3, WC, An, N0, N1, N2, N3, WN)           \
    {                                                                         \
        GISSUE(2 * ((P) + 1) + w, N0, N1, N2, N3, WN);                        \
        AISSUE((P) + 1, An);                                                  \
        asm volatile("s_waitcnt vmcnt(10)" ::: "memory");                     \
        u32x4 rv_;                                                            \
        _Pragma("unroll")                                                     \
        for (int jj = 0; jj < 4; jj++) {                                      \
            f32x2 v_ = WC[0] * unpk(C0[jj]) + WC[1] * unpk(C1[jj])            \
                     + WC[2] * unpk(C2[jj]) + WC[3] * unpk(C3[jj]);           \
            __hip_bfloat162 h2_ = __float22bfloat162_rn(make_float2(v_[0], v_[1])); \
            unsigned hu_; __builtin_memcpy(&hu_, &h2_, 4);                    \
            rv_[jj] = hu_;                                                    \
        }                                                                     \
        *reinterpret_cast<u32x4*>(&bfS[(P) & 1][w][lane * 8]) = rv_;          \
        asm volatile("s_waitcnt lgkmcnt(0)" ::: "memory");                    \
        __builtin_amdgcn_s_barrier();                                        \
        __builtin_amdgcn_sched_barrier(0);                                    \
        const short8 bf0_ = *reinterpret_cast<const short8*>(&bfS[(P) & 1][0][lane * 8]); \
        const short8 bf1_ = *reinterpret_cast<const short8*>(&bfS[(P) & 1][1][lane * 8]); \
        __builtin_amdgcn_s_setprio(1);                                        \
        acc[0] = __builtin_amdgcn_mfma_f32_32x32x16_bf16(Ac[0], bf0_, acc[0], 0, 0, 0); \
        acc[1] = __builtin_amdgcn_mfma_f32_32x32x16_bf16(Ac[1], bf0_, acc[1], 0, 0, 0); \
        acc[2] = __builtin_amdgcn_mfma_f32_32x32x16_bf16(Ac[2], bf0_, acc[2], 0, 0, 0); \
        acc[0] = __builtin_amdgcn_mfma_f32_32x32x16_bf16(Ac[3], bf1_, acc[0], 0, 0, 0); \
        acc[1] = __builtin_amdgcn_mfma_f32_32x32x16_bf16(Ac[4], bf1_, acc[1], 0, 0, 0); \
        acc[2] = __builtin_amdgcn_mfma_f32_32x32x16_bf16(Ac[5], bf1_, acc[2], 0, 0, 0); \
        __builtin_amdgcn_s_setprio(0);                                        \
    }

    short8 Aa[6], Ab[6];
    u32x4 Gx0, Gx1, Gx2, Gx3, Gy0, Gy1, Gy2, Gy3;
    f32x4 wGx, wGy;

    // prologue: pair 0's G (4) + A (6) -> 10 outstanding
    GISSUE(0 + w, Gx0, Gx1, Gx2, Gx3, wGx);
    AISSUE(0, Aa);

    for (int pr = 0; pr < 54; pr += 2) {
        PAIRSTEP(pr,     Aa, Gx0, Gx1, Gx2, Gx3, wGx, Ab, Gy0, Gy1, Gy2, Gy3, wGy);
        PAIRSTEP(pr + 1, Ab, Gy0, Gy1, Gy2, Gy3, wGy, Aa, Gx0, Gx1, Gx2, Gx3, wGx);
    }
#undef PAIRSTEP
#undef AISSUE
#undef GISSUE

    const int pos_o = (i << 7) + j0 + px_l;
#pragma unroll
    for (int m = 0; m < 3; m++) {
        const int mt32 = w * 3 + m;
#pragma unroll
        for (int reg = 0; reg < 16; reg++) {
            const int o = mt32 * 32 + (reg & 3) + ((reg >> 2) << 3) + (hi << 2);
            out[((size_t)(b * CC + o) << 14) + pos_o] = acc[m][reg] + bias[o];
        }
    }
}

// ---------------------------------------------------------------------------
extern "C" void kernel_launch(void* const* d_in, const int* in_sizes, int n_in,
                              void* d_out, int out_size, void* d_ws, size_t ws_size,
                              hipStream_t stream)
{
    const float* x_vq  = (const float*)d_in[0];
    const float* x_res = (const float*)d_in[1];
    const float* w_off = (const float*)d_in[2];
    const float* b_off = (const float*)d_in[3];
    const float* w_co  = (const float*)d_in[4];
    const float* b_co  = (const float*)d_in[5];
    const float* w_dcn = (const float*)d_in[6];
    const float* b_dcn = (const float*)d_in[7];
    float* out = (float*)d_out;

    char* ws = (char*)d_ws;
    unsigned short* xg = (unsigned short*)ws;                      // 25.17 MB
    const size_t xg_sz = (size_t)BB * 48 * HW * 8 * 2;
    unsigned short* fg = (unsigned short*)(ws + xg_sz);            // 12.58 MB
    const size_t fg_sz = (size_t)BB * 24 * HW * 8 * 2;
    float* offb = (float*)(ws + xg_sz + fg_sz);                    // 14.16 MB
    const size_t offb_sz = (size_t)BB * 108 * HW * 4;
    short* wA1 = (short*)(ws + xg_sz + fg_sz + offb_sz);           // 216*3072 + 512 pad
    short* wA2 = wA1 + (size_t)216 * 3072 + 512;                   // 108*2048
    short* wA3 = wA2 + (size_t)108 * 2048;                         // 108*4096

    to_grp_k<<<dim3(BB * 48 * HW / 256), 256, 0, stream>>>(x_vq, x_res, xg);

    // packing. conv: k = c16*144 + tap*16 + cl -> w[o][c16*16+cl][tap]
    pack_w_k<<<(216 * 6 * 64 + 255) / 256, 256, 0, stream>>>(
        w_off, wA1, 192, 3456, 144, 144, 16, 1, 9, 6, 216 * 6 * 64);
    pack_w_k<<<(108 * 4 * 64 + 255) / 256, 256, 0, stream>>>(
        w_co, wA2, 108, 1728, 144, 144, 16, 1, 9, 4, 108 * 4 * 64);
    // dcn (c16-outer order): k = c16*144 + kt*16 + cl -> w[o][c16*16+cl][kt]
    pack_w_k<<<(108 * 8 * 64 + 255) / 256, 256, 0, stream>>>(
        w_dcn, wA3, 192, 1728, 144, 144, 16, 1, 9, 8, 108 * 8 * 64);

    // conv1: xg [48 grp] -> fg [24 grp bf16]  (m-split, 4 blocks/CU)
    conv_g_k<3, 24, true><<<dim3(4, HH, BB), 128, 0, stream>>>(xg, wA1, b_off, fg, 192);
    // conv2: fg [24 grp] -> offb [108 planar f32]
    conv_g_k<2, 12, false><<<dim3(4, HH, BB), 128, 0, stream>>>(fg, wA2, b_co, offb, 108);
    // fused deform-sample + einsum (producer-split, round-14 verbatim)
    dcn_g_k<<<dim3(4, HH, BB), 128, 0, stream>>>(xg, offb, wA3, b_dcn, out);
}

// Round 17
// 169.214 us; speedup vs baseline: 1.2141x; 1.0412x over previous
//
#include <hip/hip_runtime.h>
#include <hip/hip_bf16.h>
#include <math.h>

#define HH 128
#define WW 128
#define HW 16384
#define BB 2
#define CC 192

typedef __attribute__((ext_vector_type(8)))  short short8;
typedef __attribute__((ext_vector_type(4)))  float f32x4;
typedef __attribute__((ext_vector_type(16))) float f32x16;
typedef __attribute__((ext_vector_type(2)))  float f32x2;
typedef __attribute__((ext_vector_type(4)))  unsigned u32x4;

// f32 -> bf16 bits, round-to-nearest-even
static __device__ __forceinline__ short f2bf(float f) {
    unsigned u = __float_as_uint(f);
    unsigned r = (u + 0x7FFFu + ((u >> 16) & 1u)) >> 16;
    return (short)r;
}
// u32 of 2 bf16 -> f32x2 {lo, hi}
static __device__ __forceinline__ f32x2 unpk(unsigned u) {
    f32x2 r;
    r[0] = __uint_as_float(u << 16);
    r[1] = __uint_as_float(u & 0xFFFF0000u);
    return r;
}

// async global->LDS, 16B per lane (HW-verified width). dest: wave-uniform
// base + lane*16.
static __device__ __forceinline__ void gl_lds16(const void* gsrc, void* ldst) {
    __builtin_amdgcn_global_load_lds(
        (const __attribute__((address_space(1))) unsigned*)gsrc,
        (__attribute__((address_space(3))) unsigned*)ldst, 16, 0, 0);
}

// ---------------------------------------------------------------------------
// Merged prep kernel: one launch does the grouped channels-last transpose
// AND all three weight packs (round-14 semantics, byte-identical outputs).
// Grid partition by blockIdx.x:
//   [0, 6144)            : xg[b][cg(48)][pos][8ch] bf16 transpose
//   [6144, 6144+432)     : pack wA1 (Co=192, K=3456, 8 slots)
//   [6576, 6576+216)     : pack wA2 (Co=108, K=1728, 8 slots)
//   [6792, 6792+216)     : pack wA3 (Co=192, K=1728, 8 slots)
// pack: wp[chunk*4096 + slot*512 + lane*8 + r], o = slot*32+(lane&31),
// k = chunk*16 + (lane>>5)*8 + r; src = w[o*so + (k/144)*144 + ((k%144)/16)
//      + ((k%144)%16)*9]  (conv/dcn share d1=144,s1=144,d2=16,s2=1,s3=9).
// ---------------------------------------------------------------------------
static __device__ __forceinline__ void pack_body(
    const float* __restrict__ w, short* __restrict__ wp, int Co, int so, int idx)
{
    const int lane  = idx & 63;
    const int slot  = (idx >> 6) & 7;
    const int chunk = idx >> 9;
    const int o     = slot * 32 + (lane & 31);
    const int k0    = chunk * 16 + ((lane >> 5) << 3);
    short8 v;
#pragma unroll
    for (int r = 0; r < 8; r++) {
        const int k = k0 + r;
        float f = 0.f;
        if (o < Co) {
            const int rem = k % 144;
            f = w[(size_t)o * so + (k / 144) * 144 + (rem / 16) * 1 + (rem % 16) * 9];
        }
        v[r] = f2bf(f);
    }
    *reinterpret_cast<short8*>(wp + (size_t)idx * 8) = v;
}

__global__ __launch_bounds__(256) void prep_k(
    const float* __restrict__ xv, const float* __restrict__ xr,
    unsigned short* __restrict__ xg,
    const float* __restrict__ w_off, short* __restrict__ wA1,
    const float* __restrict__ w_co,  short* __restrict__ wA2,
    const float* __restrict__ w_dcn, short* __restrict__ wA3)
{
    const int bid = blockIdx.x;
    const int t   = threadIdx.x;
    if (bid < 6144) {
        const int idx = bid * 256 + t;           // (b*48+cg)*HW + pos
        const int pos = idx & (HW - 1);
        const int cgb = idx >> 14;
        const int cg  = cgb % 48;
        const int b   = cgb / 48;
        short8 v;
#pragma unroll
        for (int r = 0; r < 8; r++) {
            const int c = cg * 8 + r;
            const float f = (c < 192)
                ? xv[((size_t)(b * 192 + c) << 14) + pos]
                : xr[((size_t)(b * 192 + (c - 192)) << 14) + pos];
            v[r] = f2bf(f);
        }
        *reinterpret_cast<short8*>(xg + (size_t)idx * 8) = v;
    } else if (bid < 6144 + 432) {
        pack_body(w_off, wA1, 192, 3456, (bid - 6144) * 256 + t);      // 216*512
    } else if (bid < 6144 + 432 + 216) {
        pack_body(w_co,  wA2, 108, 1728, (bid - 6576) * 256 + t);      // 108*512
    } else {
        pack_body(w_dcn, wA3, 192, 1728, (bid - 6792) * 256 + t);      // 108*512
    }
}

// ---------------------------------------------------------------------------
// 3x3 conv (pad 1), implicit GEMM, 32x32x16 MFMA, grouped-CL input.
// Round-14 structure VERBATIM (best measured, 174.2 us total): block =
// 256 thr (4 waves: mg=wid>>1, nt=wid&1), 64 px per (b,i,j0); grid 512 ->
// 2 independent blocks/CU. TWO chunks per barrier: paired LDS buffers
// Pbuf[3][2][4096], 6-deep B reg rotation. Queue invariant at each vmcnt:
// [B(p+1)2, S(p+1)4, B(p+2)2] = 8 outstanding -> vmcnt(8). setprio around
// the MFMA cluster.
// ---------------------------------------------------------------------------
template<int MTW, int NC16, bool OUT_GRP>
__global__ __launch_bounds__(256, 2) void conv_g_k(
    const unsigned short* __restrict__ xg,
    const short* __restrict__ wA, const float* __restrict__ bias,
    void* __restrict__ outp, int Cout)
{
    __shared__ __align__(16) short Pbuf[3][2][4096];

    const int t    = threadIdx.x;
    const int lane = t & 63;
    const int wid  = t >> 6;
    const int mg   = wid >> 1;
    const int nt   = wid & 1;
    // XCD swizzle: nwg = 2*HH*BB = 512
    const int lin  = (blockIdx.z * HH + blockIdx.y) * 2 + blockIdx.x;
    const int og_  = (lin & 7) * 64 + (lin >> 3);
    const int j0   = (og_ & 1) * 64;
    const int i    = (og_ >> 1) & (HH - 1);
    const int b    = og_ >> 8;
    const int px   = j0 + (nt << 5) + (lane & 31);
    const int hi   = lane >> 5;
    constexpr int NQ = NC16 * 9;
    constexpr int NP = NQ / 2;   // pairs (divisible by 3)

    const unsigned short* __restrict__ xgb = xg + (size_t)b * (NC16 * 2) * HW * 8;

    f32x16 acc[MTW];
#pragma unroll
    for (int m = 0; m < MTW; m++)
#pragma unroll
        for (int r = 0; r < 16; r++) acc[m][r] = 0.f;

    auto loadB = [&](int qq, short8& dst, bool& vm) {
        const int c16 = qq / 9;
        const int tap = qq - c16 * 9;
        const int iy  = i + tap / 3 - 1;
        const int jx  = px + tap % 3 - 1;
        vm = ((unsigned)iy < HH) && ((unsigned)jx < WW);
        const int iyc = min(max(iy, 0), HH - 1);
        const int jxc = min(max(jx, 0), WW - 1);
        dst = *reinterpret_cast<const short8*>(
            xgb + ((size_t)(c16 * 2 + hi) * HW + (iyc << 7) + jxc) * 8);
    };
    auto stage2 = [&](int chunk, int pb, int sl) {
        gl_lds16(wA + (size_t)chunk * 4096 + t * 8,         &Pbuf[pb][sl][wid * 512]);
        gl_lds16(wA + (size_t)chunk * 4096 + (t + 256) * 8, &Pbuf[pb][sl][2048 + wid * 512]);
    };

    short8 B0, B1, B2, B3, B4, B5;
    bool M0, M1, M2, M3, M4, M5;

    // prologue order (queue invariant): S(pair0)4, B(pair0)2, S(pair1)4, B(pair1)2
    stage2(0, 0, 0); stage2(1, 0, 1);
    loadB(0, B0, M0); loadB(1, B1, M1);
    stage2(2, 1, 0); stage2(3, 1, 1);
    loadB(2, B2, M2); loadB(3, B3, M3);

#define CCHUNK(IBUF, SL, BC, MC)                                              \
    {                                                                         \
        short8 bF = BC;                                                       \
        if (!MC) {                                                            \
            _Pragma("unroll")                                                 \
            for (int r = 0; r < 8; r++) bF[r] = 0;                            \
        }                                                                     \
        const short* ab_ = &Pbuf[IBUF][SL][(mg * MTW) * 512 + lane * 8];      \
        short8 aF[MTW];                                                       \
        _Pragma("unroll")                                                     \
        for (int m = 0; m < MTW; m++)                                         \
            aF[m] = *reinterpret_cast<const short8*>(ab_ + m * 512);          \
        __builtin_amdgcn_s_setprio(1);                                        \
        _Pragma("unroll")                                                     \
        for (int m = 0; m < MTW; m++)                                         \
            acc[m] = __builtin_amdgcn_mfma_f32_32x32x16_bf16(aF[m], bF, acc[m], 0, 0, 0); \
        __builtin_amdgcn_s_setprio(0);                                        \
    }

#define PSTEP(P, IBUF, SBUF, Bc0, Mc0, Bc1, Mc1, Bn0, Mn0, Bn1, Mn1)          \
    {                                                                         \
        loadB(min(2 * ((P) + 2),     NQ - 1), Bn0, Mn0);                      \
        loadB(min(2 * ((P) + 2) + 1, NQ - 1), Bn1, Mn1);                      \
        asm volatile("s_waitcnt vmcnt(8)" ::: "memory");                      \
        __builtin_amdgcn_s_barrier();                                         \
        __builtin_amdgcn_sched_barrier(0);                                    \
        const int sc0_ = min(2 * ((P) + 2),     NQ - 1);                      \
        const int sc1_ = min(2 * ((P) + 2) + 1, NQ - 1);                      \
        stage2(sc0_, SBUF, 0); stage2(sc1_, SBUF, 1);                         \
        CCHUNK(IBUF, 0, Bc0, Mc0);                                            \
        CCHUNK(IBUF, 1, Bc1, Mc1);                                            \
    }

    for (int pp = 0; pp < NP; pp += 3) {
        PSTEP(pp + 0, 0, 2, B0, M0, B1, M1, B4, M4, B5, M5);
        PSTEP(pp + 1, 1, 0, B2, M2, B3, M3, B0, M0, B1, M1);
        PSTEP(pp + 2, 2, 1, B4, M4, B5, M5, B2, M2, B3, M3);
    }
#undef PSTEP
#undef CCHUNK

    // store. C/D: col = lane&31 -> px ; row = (reg&3)+8*(reg>>2)+4*hi -> o.
    const int pos_o = (i << 7) + px;
    if constexpr (OUT_GRP) {
        unsigned short* fg = (unsigned short*)outp;
#pragma unroll
        for (int m = 0; m < MTW; m++) {
            const int mt32 = mg * MTW + m;
#pragma unroll
            for (int g = 0; g < 4; g++) {
                const int ob = mt32 * 32 + 8 * g + 4 * hi;
                const unsigned s0 = (unsigned short)f2bf(acc[m][4 * g + 0] + bias[ob + 0]);
                const unsigned s1 = (unsigned short)f2bf(acc[m][4 * g + 1] + bias[ob + 1]);
                const unsigned s2 = (unsigned short)f2bf(acc[m][4 * g + 2] + bias[ob + 2]);
                const unsigned s3 = (unsigned short)f2bf(acc[m][4 * g + 3] + bias[ob + 3]);
                const int cg = mt32 * 4 + g;
                *reinterpret_cast<uint2*>(
                    fg + ((size_t)(b * (Cout >> 3) + cg) * HW + pos_o) * 8 + 4 * hi) =
                    make_uint2(s0 | (s1 << 16), s2 | (s3 << 16));
            }
        }
    } else {
        float* of = (float*)outp;
#pragma unroll
        for (int m = 0; m < MTW; m++) {
            const int mt32 = mg * MTW + m;
#pragma unroll
            for (int reg = 0; reg < 16; reg++) {
                const int o = mt32 * 32 + (reg & 3) + ((reg >> 2) << 3) + (hi << 2);
                if (o < Cout)
                    of[((size_t)(b * Cout + o) << 14) + pos_o] = acc[m][reg] + bias[o];
            }
        }
    }
}

// ---------------------------------------------------------------------------
// Fused deform-sample + einsum, 32x32x16 MFMA, producer-split bF sharing.
// (Round-14 verbatim — passing at 174 us.) Block = 128 thr (2 waves),
// 32 px x 192 out-ch; grid 1024 -> 4 blocks/CU. Per pair per wave issue:
// 4 G + 6 A -> exact vmcnt(10).
// ---------------------------------------------------------------------------
__global__ __launch_bounds__(128, 2) void dcn_g_k(
    const unsigned short* __restrict__ xg, const float* __restrict__ off,
    const short* __restrict__ wA, const float* __restrict__ bias,
    float* __restrict__ out)
{
    __shared__ __align__(16) f32x4 eW[1152];      // 18.4 KB (36 gk x 32 px)
    __shared__ __align__(8)  uint2 eO[1152];      //  9.2 KB
    __shared__ __align__(16) short bfS[2][2][512];//  4 KB  [buf][subchunk][.]

    const int t    = threadIdx.x;
    const int lane = t & 63;
    const int w    = t >> 6;     // wave id = producer sub-chunk = m-half
    // XCD swizzle: nwg = 4*HH*BB = 1024
    const int lin  = (blockIdx.z * HH + blockIdx.y) * 4 + blockIdx.x;
    const int og_  = (lin & 7) * 128 + (lin >> 3);
    const int jt   = og_ & 3;
    const int i    = (og_ >> 2) & (HH - 1);
    const int b    = og_ >> 9;
    const int j0   = jt * 32;

    // ---- A1: bilinear entries (identical math to verified rounds 2-16) ----
    for (int e = t; e < 1152; e += 128) {
        const int p  = e & 31;
        const int gk = e >> 5;               // g*9 + kt
        const int kt = gk % 9;
        const int j  = j0 + p;
        const size_t sp = (size_t)b * 108 * HW + (size_t)gk * HW + (i << 7) + j;
        const float dy = off[sp];
        const float dx = off[sp + (size_t)36 * HW];
        const float mv = off[sp + (size_t)72 * HW];
        const float m  = 1.f / (1.f + expf(-mv));
        const float py = (float)(i + kt / 3 - 1) + dy;
        const float px = (float)(j + kt % 3 - 1) + dx;
        const float y0f = floorf(py), x0f = floorf(px);
        const float ly = py - y0f, lx = px - x0f;
        const int y0 = (int)y0f, x0 = (int)x0f;
        const float vy0 = (y0 >= 0 && y0 < HH) ? 1.f : 0.f;
        const float vy1 = (y0 + 1 >= 0 && y0 + 1 < HH) ? 1.f : 0.f;
        const float vx0 = (x0 >= 0 && x0 < WW) ? 1.f : 0.f;
        const float vx1 = (x0 + 1 >= 0 && x0 + 1 < WW) ? 1.f : 0.f;
        f32x4 w4;
        w4[0] = (1.f - ly) * (1.f - lx) * m * vy0 * vx0;
        w4[1] = (1.f - ly) * lx         * m * vy0 * vx1;
        w4[2] = ly         * (1.f - lx) * m * vy1 * vx0;
        w4[3] = ly         * lx         * m * vy1 * vx1;
        const int yc0 = min(max(y0, 0), HH - 1);
        const int yc1 = min(max(y0 + 1, 0), HH - 1);
        const int xc0 = min(max(x0, 0), WW - 1);
        const int xc1 = min(max(x0 + 1, 0), WW - 1);
        eW[e] = w4;
        eO[e] = make_uint2((unsigned)((yc0 << 7) + xc0) | ((unsigned)((yc0 << 7) + xc1) << 16),
                           (unsigned)((yc1 << 7) + xc0) | ((unsigned)((yc1 << 7) + xc1) << 16));
    }
    __syncthreads();

    const int px_l = lane & 31;
    const int hi   = lane >> 5;
    const unsigned short* __restrict__ xgb = xg + (size_t)b * 48 * HW * 8;

    f32x16 acc[3];
#pragma unroll
    for (int m = 0; m < 3; m++)
#pragma unroll
        for (int r = 0; r < 16; r++) acc[m][r] = 0.f;

    // my gather chunk for pair P is 2P + w
#define GISSUE(QQ, N0, N1, N2, N3, WN)                                        \
    {                                                                         \
        const int qn_   = min((QQ), 107);                                     \
        const int c16n_ = qn_ / 9;                                            \
        const int ktn_  = qn_ - 9 * c16n_;                                    \
        const int e_    = ((c16n_ / 3) * 9 + ktn_) * 32 + px_l;               \
        const uint2 o_  = eO[e_];                                             \
        WN = eW[e_];                                                          \
        const unsigned short* base_ = xgb + (size_t)(c16n_ * 2 + hi) * (HW * 8); \
        N0 = *reinterpret_cast<const u32x4*>(base_ + (size_t)(o_.x & 0xFFFFu) * 8); \
        N1 = *reinterpret_cast<const u32x4*>(base_ + (size_t)(o_.x >> 16) * 8);     \
        N2 = *reinterpret_cast<const u32x4*>(base_ + (size_t)(o_.y & 0xFFFFu) * 8); \
        N3 = *reinterpret_cast<const u32x4*>(base_ + (size_t)(o_.y >> 16) * 8);     \
    }

    // A frags for pair P (chunks 2P, 2P+1), m-half w: 6 b128 loads
#define AISSUE(PP, DST)                                                       \
    {                                                                         \
        const short* a0_ = wA + (size_t)min(2 * (PP),     107) * 4096 + (w * 3) * 512 + lane * 8; \
        const short* a1_ = wA + (size_t)min(2 * (PP) + 1, 107) * 4096 + (w * 3) * 512 + lane * 8; \
        DST[0] = *reinterpret_cast<const short8*>(a0_);                       \
        DST[1] = *reinterpret_cast<const short8*>(a0_ + 512);                 \
        DST[2] = *reinterpret_cast<const short8*>(a0_ + 1024);                \
        DST[3] = *reinterpret_cast<const short8*>(a1_);                       \
        DST[4] = *reinterpret_cast<const short8*>(a1_ + 512);                 \
        DST[5] = *reinterpret_cast<const short8*>(a1_ + 1024);                \
    }

#define PAIRSTEP(P, Ac, C0, C1, C2, C3, WC, An, N0, N1, N2, N3, WN)           \
    {                                                                         \
        GISSUE(2 * ((P) + 1) + w, N0, N1, N2, N3, WN);                        \
        AISSUE((P) + 1, An);                                                  \
        asm volatile("s_waitcnt vmcnt(10)" ::: "memory");                     \
        u32x4 rv_;                                                            \
        _Pragma("unroll")                                                     \
        for (int jj = 0; jj < 4; jj++) {                                      \
            f32x2 v_ = WC[0] * unpk(C0[jj]) + WC[1] * unpk(C1[jj])            \
                     + WC[2] * unpk(C2[jj]) + WC[3] * unpk(C3[jj]);           \
            __hip_bfloat162 h2_ = __float22bfloat162_rn(make_float2(v_[0], v_[1])); \
            unsigned hu_; __builtin_memcpy(&hu_, &h2_, 4);                    \
            rv_[jj] = hu_;                                                    \
        }                                                                     \
        *reinterpret_cast<u32x4*>(&bfS[(P) & 1][w][lane * 8]) = rv_;          \
        asm volatile("s_waitcnt lgkmcnt(0)" ::: "memory");                    \
        __builtin_amdgcn_s_barrier();                                         \
        __builtin_amdgcn_sched_barrier(0);                                    \
        const short8 bf0_ = *reinterpret_cast<const short8*>(&bfS[(P) & 1][0][lane * 8]); \
        const short8 bf1_ = *reinterpret_cast<const short8*>(&bfS[(P) & 1][1][lane * 8]); \
        __builtin_amdgcn_s_setprio(1);                                        \
        acc[0] = __builtin_amdgcn_mfma_f32_32x32x16_bf16(Ac[0], bf0_, acc[0], 0, 0, 0); \
        acc[1] = __builtin_amdgcn_mfma_f32_32x32x16_bf16(Ac[1], bf0_, acc[1], 0, 0, 0); \
        acc[2] = __builtin_amdgcn_mfma_f32_32x32x16_bf16(Ac[2], bf0_, acc[2], 0, 0, 0); \
        acc[0] = __builtin_amdgcn_mfma_f32_32x32x16_bf16(Ac[3], bf1_, acc[0], 0, 0, 0); \
        acc[1] = __builtin_amdgcn_mfma_f32_32x32x16_bf16(Ac[4], bf1_, acc[1], 0, 0, 0); \
        acc[2] = __builtin_amdgcn_mfma_f32_32x32x16_bf16(Ac[5], bf1_, acc[2], 0, 0, 0); \
        __builtin_amdgcn_s_setprio(0);                                        \
    }

    short8 Aa[6], Ab[6];
    u32x4 Gx0, Gx1, Gx2, Gx3, Gy0, Gy1, Gy2, Gy3;
    f32x4 wGx, wGy;

    // prologue: pair 0's G (4) + A (6) -> 10 outstanding
    GISSUE(0 + w, Gx0, Gx1, Gx2, Gx3, wGx);
    AISSUE(0, Aa);

    for (int pr = 0; pr < 54; pr += 2) {
        PAIRSTEP(pr,     Aa, Gx0, Gx1, Gx2, Gx3, wGx, Ab, Gy0, Gy1, Gy2, Gy3, wGy);
        PAIRSTEP(pr + 1, Ab, Gy0, Gy1, Gy2, Gy3, wGy, Aa, Gx0, Gx1, Gx2, Gx3, wGx);
    }
#undef PAIRSTEP
#undef AISSUE
#undef GISSUE

    const int pos_o = (i << 7) + j0 + px_l;
#pragma unroll
    for (int m = 0; m < 3; m++) {
        const int mt32 = w * 3 + m;
#pragma unroll
        for (int reg = 0; reg < 16; reg++) {
            const int o = mt32 * 32 + (reg & 3) + ((reg >> 2) << 3) + (hi << 2);
            out[((size_t)(b * CC + o) << 14) + pos_o] = acc[m][reg] + bias[o];
        }
    }
}

// ---------------------------------------------------------------------------
extern "C" void kernel_launch(void* const* d_in, const int* in_sizes, int n_in,
                              void* d_out, int out_size, void* d_ws, size_t ws_size,
                              hipStream_t stream)
{
    const float* x_vq  = (const float*)d_in[0];
    const float* x_res = (const float*)d_in[1];
    const float* w_off = (const float*)d_in[2];
    const float* b_off = (const float*)d_in[3];
    const float* w_co  = (const float*)d_in[4];
    const float* b_co  = (const float*)d_in[5];
    const float* w_dcn = (const float*)d_in[6];
    const float* b_dcn = (const float*)d_in[7];
    float* out = (float*)d_out;

    char* ws = (char*)d_ws;
    unsigned short* xg = (unsigned short*)ws;                      // 25.17 MB
    const size_t xg_sz = (size_t)BB * 48 * HW * 8 * 2;
    unsigned short* fg = (unsigned short*)(ws + xg_sz);            // 12.58 MB
    const size_t fg_sz = (size_t)BB * 24 * HW * 8 * 2;
    float* offb = (float*)(ws + xg_sz + fg_sz);                    // 14.16 MB
    const size_t offb_sz = (size_t)BB * 108 * HW * 4;
    short* wA1 = (short*)(ws + xg_sz + fg_sz + offb_sz);           // 216*4096
    short* wA2 = wA1 + (size_t)216 * 4096;                         // 108*4096
    short* wA3 = wA2 + (size_t)108 * 4096;                         // 108*4096

    // merged prep: transpose + all three packs in ONE launch
    prep_k<<<dim3(6144 + 432 + 216 + 216), 256, 0, stream>>>(
        x_vq, x_res, xg, w_off, wA1, w_co, wA2, w_dcn, wA3);

    // conv1: xg [48 grp] -> fg [24 grp bf16]
    conv_g_k<3, 24, true><<<dim3(2, HH, BB), 256, 0, stream>>>(xg, wA1, b_off, fg, 192);
    // conv2: fg [24 grp] -> offb [108 planar f32]
    conv_g_k<2, 12, false><<<dim3(2, HH, BB), 256, 0, stream>>>(fg, wA2, b_co, offb, 108);
    // fused deform-sample + einsum (producer-split, round-14 verbatim)
    dcn_g_k<<<dim3(4, HH, BB), 128, 0, stream>>>(xg, offb, wA3, b_dcn, out);
}

// Round 18
// 168.756 us; speedup vs baseline: 1.2174x; 1.0027x over previous
//
#include <hip/hip_runtime.h>
#include <hip/hip_bf16.h>
#include <math.h>

#define HH 128
#define WW 128
#define HW 16384
#define BB 2
#define CC 192

typedef __attribute__((ext_vector_type(8)))  short short8;
typedef __attribute__((ext_vector_type(4)))  float f32x4;
typedef __attribute__((ext_vector_type(16))) float f32x16;
typedef __attribute__((ext_vector_type(2)))  float f32x2;
typedef __attribute__((ext_vector_type(4)))  unsigned u32x4;

// f32 -> bf16 bits, round-to-nearest-even
static __device__ __forceinline__ short f2bf(float f) {
    unsigned u = __float_as_uint(f);
    unsigned r = (u + 0x7FFFu + ((u >> 16) & 1u)) >> 16;
    return (short)r;
}
// u32 of 2 bf16 -> f32x2 {lo, hi}
static __device__ __forceinline__ f32x2 unpk(unsigned u) {
    f32x2 r;
    r[0] = __uint_as_float(u << 16);
    r[1] = __uint_as_float(u & 0xFFFF0000u);
    return r;
}
// fast sigmoid: v_exp_f32 + v_rcp_f32 (rel err ~1e-6, << bf16 rounding)
static __device__ __forceinline__ float fsigmoid(float x) {
    return __builtin_amdgcn_rcpf(1.f + __expf(-x));
}

// async global->LDS, 16B per lane (HW-verified width). dest: wave-uniform
// base + lane*16.
static __device__ __forceinline__ void gl_lds16(const void* gsrc, void* ldst) {
    __builtin_amdgcn_global_load_lds(
        (const __attribute__((address_space(1))) unsigned*)gsrc,
        (__attribute__((address_space(3))) unsigned*)ldst, 16, 0, 0);
}

// ---------------------------------------------------------------------------
// Merged prep kernel: one launch does the grouped channels-last transpose
// AND all three weight packs (round-14 semantics, byte-identical outputs).
// Grid partition by blockIdx.x:
//   [0, 6144)            : xg[b][cg(48)][pos][8ch] bf16 transpose
//   [6144, 6144+432)     : pack wA1 (Co=192, K=3456, 8 slots)
//   [6576, 6576+216)     : pack wA2 (Co=108, K=1728, 8 slots)
//   [6792, 6792+216)     : pack wA3 (Co=192, K=1728, 8 slots)
// pack: wp[chunk*4096 + slot*512 + lane*8 + r], o = slot*32+(lane&31),
// k = chunk*16 + (lane>>5)*8 + r; src = w[o*so + (k/144)*144 + ((k%144)/16)
//      + ((k%144)%16)*9]  (conv/dcn share d1=144,s1=144,d2=16,s2=1,s3=9).
// ---------------------------------------------------------------------------
static __device__ __forceinline__ void pack_body(
    const float* __restrict__ w, short* __restrict__ wp, int Co, int so, int idx)
{
    const int lane  = idx & 63;
    const int slot  = (idx >> 6) & 7;
    const int chunk = idx >> 9;
    const int o     = slot * 32 + (lane & 31);
    const int k0    = chunk * 16 + ((lane >> 5) << 3);
    short8 v;
#pragma unroll
    for (int r = 0; r < 8; r++) {
        const int k = k0 + r;
        float f = 0.f;
        if (o < Co) {
            const int rem = k % 144;
            f = w[(size_t)o * so + (k / 144) * 144 + (rem / 16) * 1 + (rem % 16) * 9];
        }
        v[r] = f2bf(f);
    }
    *reinterpret_cast<short8*>(wp + (size_t)idx * 8) = v;
}

__global__ __launch_bounds__(256) void prep_k(
    const float* __restrict__ xv, const float* __restrict__ xr,
    unsigned short* __restrict__ xg,
    const float* __restrict__ w_off, short* __restrict__ wA1,
    const float* __restrict__ w_co,  short* __restrict__ wA2,
    const float* __restrict__ w_dcn, short* __restrict__ wA3)
{
    const int bid = blockIdx.x;
    const int t   = threadIdx.x;
    if (bid < 6144) {
        const int idx = bid * 256 + t;           // (b*48+cg)*HW + pos
        const int pos = idx & (HW - 1);
        const int cgb = idx >> 14;
        const int cg  = cgb % 48;
        const int b   = cgb / 48;
        short8 v;
#pragma unroll
        for (int r = 0; r < 8; r++) {
            const int c = cg * 8 + r;
            const float f = (c < 192)
                ? xv[((size_t)(b * 192 + c) << 14) + pos]
                : xr[((size_t)(b * 192 + (c - 192)) << 14) + pos];
            v[r] = f2bf(f);
        }
        *reinterpret_cast<short8*>(xg + (size_t)idx * 8) = v;
    } else if (bid < 6144 + 432) {
        pack_body(w_off, wA1, 192, 3456, (bid - 6144) * 256 + t);      // 216*512
    } else if (bid < 6144 + 432 + 216) {
        pack_body(w_co,  wA2, 108, 1728, (bid - 6576) * 256 + t);      // 108*512
    } else {
        pack_body(w_dcn, wA3, 192, 1728, (bid - 6792) * 256 + t);      // 108*512
    }
}

// ---------------------------------------------------------------------------
// 3x3 conv (pad 1), implicit GEMM, 32x32x16 MFMA, grouped-CL input.
// Round-14 structure VERBATIM (best measured): block = 256 thr (4 waves:
// mg=wid>>1, nt=wid&1), 64 px per (b,i,j0); grid 512 -> 2 independent
// blocks/CU. TWO chunks per barrier: paired LDS buffers Pbuf[3][2][4096],
// 6-deep B reg rotation. Queue invariant at each vmcnt:
// [B(p+1)2, S(p+1)4, B(p+2)2] = 8 outstanding -> vmcnt(8). setprio around
// the MFMA cluster.
// ---------------------------------------------------------------------------
template<int MTW, int NC16, bool OUT_GRP>
__global__ __launch_bounds__(256, 2) void conv_g_k(
    const unsigned short* __restrict__ xg,
    const short* __restrict__ wA, const float* __restrict__ bias,
    void* __restrict__ outp, int Cout)
{
    __shared__ __align__(16) short Pbuf[3][2][4096];

    const int t    = threadIdx.x;
    const int lane = t & 63;
    const int wid  = t >> 6;
    const int mg   = wid >> 1;
    const int nt   = wid & 1;
    // XCD swizzle: nwg = 2*HH*BB = 512
    const int lin  = (blockIdx.z * HH + blockIdx.y) * 2 + blockIdx.x;
    const int og_  = (lin & 7) * 64 + (lin >> 3);
    const int j0   = (og_ & 1) * 64;
    const int i    = (og_ >> 1) & (HH - 1);
    const int b    = og_ >> 8;
    const int px   = j0 + (nt << 5) + (lane & 31);
    const int hi   = lane >> 5;
    constexpr int NQ = NC16 * 9;
    constexpr int NP = NQ / 2;   // pairs (divisible by 3)

    const unsigned short* __restrict__ xgb = xg + (size_t)b * (NC16 * 2) * HW * 8;

    f32x16 acc[MTW];
#pragma unroll
    for (int m = 0; m < MTW; m++)
#pragma unroll
        for (int r = 0; r < 16; r++) acc[m][r] = 0.f;

    auto loadB = [&](int qq, short8& dst, bool& vm) {
        const int c16 = qq / 9;
        const int tap = qq - c16 * 9;
        const int iy  = i + tap / 3 - 1;
        const int jx  = px + tap % 3 - 1;
        vm = ((unsigned)iy < HH) && ((unsigned)jx < WW);
        const int iyc = min(max(iy, 0), HH - 1);
        const int jxc = min(max(jx, 0), WW - 1);
        dst = *reinterpret_cast<const short8*>(
            xgb + ((size_t)(c16 * 2 + hi) * HW + (iyc << 7) + jxc) * 8);
    };
    auto stage2 = [&](int chunk, int pb, int sl) {
        gl_lds16(wA + (size_t)chunk * 4096 + t * 8,         &Pbuf[pb][sl][wid * 512]);
        gl_lds16(wA + (size_t)chunk * 4096 + (t + 256) * 8, &Pbuf[pb][sl][2048 + wid * 512]);
    };

    short8 B0, B1, B2, B3, B4, B5;
    bool M0, M1, M2, M3, M4, M5;

    // prologue order (queue invariant): S(pair0)4, B(pair0)2, S(pair1)4, B(pair1)2
    stage2(0, 0, 0); stage2(1, 0, 1);
    loadB(0, B0, M0); loadB(1, B1, M1);
    stage2(2, 1, 0); stage2(3, 1, 1);
    loadB(2, B2, M2); loadB(3, B3, M3);

#define CCHUNK(IBUF, SL, BC, MC)                                              \
    {                                                                         \
        short8 bF = BC;                                                       \
        if (!MC) {                                                            \
            _Pragma("unroll")                                                 \
            for (int r = 0; r < 8; r++) bF[r] = 0;                            \
        }                                                                     \
        const short* ab_ = &Pbuf[IBUF][SL][(mg * MTW) * 512 + lane * 8];      \
        short8 aF[MTW];                                                       \
        _Pragma("unroll")                                                     \
        for (int m = 0; m < MTW; m++)                                         \
            aF[m] = *reinterpret_cast<const short8*>(ab_ + m * 512);          \
        __builtin_amdgcn_s_setprio(1);                                        \
        _Pragma("unroll")                                                     \
        for (int m = 0; m < MTW; m++)                                         \
            acc[m] = __builtin_amdgcn_mfma_f32_32x32x16_bf16(aF[m], bF, acc[m], 0, 0, 0); \
        __builtin_amdgcn_s_setprio(0);                                        \
    }

#define PSTEP(P, IBUF, SBUF, Bc0, Mc0, Bc1, Mc1, Bn0, Mn0, Bn1, Mn1)          \
    {                                                                         \
        loadB(min(2 * ((P) + 2),     NQ - 1), Bn0, Mn0);                      \
        loadB(min(2 * ((P) + 2) + 1, NQ - 1), Bn1, Mn1);                      \
        asm volatile("s_waitcnt vmcnt(8)" ::: "memory");                      \
        __builtin_amdgcn_s_barrier();                                         \
        __builtin_amdgcn_sched_barrier(0);                                    \
        const int sc0_ = min(2 * ((P) + 2),     NQ - 1);                      \
        const int sc1_ = min(2 * ((P) + 2) + 1, NQ - 1);                      \
        stage2(sc0_, SBUF, 0); stage2(sc1_, SBUF, 1);                         \
        CCHUNK(IBUF, 0, Bc0, Mc0);                                            \
        CCHUNK(IBUF, 1, Bc1, Mc1);                                            \
    }

    for (int pp = 0; pp < NP; pp += 3) {
        PSTEP(pp + 0, 0, 2, B0, M0, B1, M1, B4, M4, B5, M5);
        PSTEP(pp + 1, 1, 0, B2, M2, B3, M3, B0, M0, B1, M1);
        PSTEP(pp + 2, 2, 1, B4, M4, B5, M5, B2, M2, B3, M3);
    }
#undef PSTEP
#undef CCHUNK

    // store. C/D: col = lane&31 -> px ; row = (reg&3)+8*(reg>>2)+4*hi -> o.
    const int pos_o = (i << 7) + px;
    if constexpr (OUT_GRP) {
        unsigned short* fg = (unsigned short*)outp;
#pragma unroll
        for (int m = 0; m < MTW; m++) {
            const int mt32 = mg * MTW + m;
#pragma unroll
            for (int g = 0; g < 4; g++) {
                const int ob = mt32 * 32 + 8 * g + 4 * hi;
                const unsigned s0 = (unsigned short)f2bf(acc[m][4 * g + 0] + bias[ob + 0]);
                const unsigned s1 = (unsigned short)f2bf(acc[m][4 * g + 1] + bias[ob + 1]);
                const unsigned s2 = (unsigned short)f2bf(acc[m][4 * g + 2] + bias[ob + 2]);
                const unsigned s3 = (unsigned short)f2bf(acc[m][4 * g + 3] + bias[ob + 3]);
                const int cg = mt32 * 4 + g;
                *reinterpret_cast<uint2*>(
                    fg + ((size_t)(b * (Cout >> 3) + cg) * HW + pos_o) * 8 + 4 * hi) =
                    make_uint2(s0 | (s1 << 16), s2 | (s3 << 16));
            }
        }
    } else {
        float* of = (float*)outp;
#pragma unroll
        for (int m = 0; m < MTW; m++) {
            const int mt32 = mg * MTW + m;
#pragma unroll
            for (int reg = 0; reg < 16; reg++) {
                const int o = mt32 * 32 + (reg & 3) + ((reg >> 2) << 3) + (hi << 2);
                if (o < Cout)
                    of[((size_t)(b * Cout + o) << 14) + pos_o] = acc[m][reg] + bias[o];
            }
        }
    }
}

// ---------------------------------------------------------------------------
// Fused deform-sample + einsum, 32x32x16 MFMA, producer-split bF sharing.
// (Round-14 structure; A1 uses fast sigmoid.) Block = 128 thr (2 waves),
// 32 px x 192 out-ch; grid 1024 -> 4 blocks/CU. Per pair per wave issue:
// 4 G + 6 A -> exact vmcnt(10).
// ---------------------------------------------------------------------------
__global__ __launch_bounds__(128, 2) void dcn_g_k(
    const unsigned short* __restrict__ xg, const float* __restrict__ off,
    const short* __restrict__ wA, const float* __restrict__ bias,
    float* __restrict__ out)
{
    __shared__ __align__(16) f32x4 eW[1152];      // 18.4 KB (36 gk x 32 px)
    __shared__ __align__(8)  uint2 eO[1152];      //  9.2 KB
    __shared__ __align__(16) short bfS[2][2][512];//  4 KB  [buf][subchunk][.]

    const int t    = threadIdx.x;
    const int lane = t & 63;
    const int w    = t >> 6;     // wave id = producer sub-chunk = m-half
    // XCD swizzle: nwg = 4*HH*BB = 1024
    const int lin  = (blockIdx.z * HH + blockIdx.y) * 4 + blockIdx.x;
    const int og_  = (lin & 7) * 128 + (lin >> 3);
    const int jt   = og_ & 3;
    const int i    = (og_ >> 2) & (HH - 1);
    const int b    = og_ >> 9;
    const int j0   = jt * 32;

    // ---- A1: bilinear entries (same math; fast sigmoid) -------------------
    for (int e = t; e < 1152; e += 128) {
        const int p  = e & 31;
        const int gk = e >> 5;               // g*9 + kt
        const int kt = gk % 9;
        const int j  = j0 + p;
        const size_t sp = (size_t)b * 108 * HW + (size_t)gk * HW + (i << 7) + j;
        const float dy = off[sp];
        const float dx = off[sp + (size_t)36 * HW];
        const float mv = off[sp + (size_t)72 * HW];
        const float m  = fsigmoid(mv);
        const float py = (float)(i + kt / 3 - 1) + dy;
        const float px = (float)(j + kt % 3 - 1) + dx;
        const float y0f = floorf(py), x0f = floorf(px);
        const float ly = py - y0f, lx = px - x0f;
        const int y0 = (int)y0f, x0 = (int)x0f;
        const float vy0 = (y0 >= 0 && y0 < HH) ? 1.f : 0.f;
        const float vy1 = (y0 + 1 >= 0 && y0 + 1 < HH) ? 1.f : 0.f;
        const float vx0 = (x0 >= 0 && x0 < WW) ? 1.f : 0.f;
        const float vx1 = (x0 + 1 >= 0 && x0 + 1 < WW) ? 1.f : 0.f;
        f32x4 w4;
        w4[0] = (1.f - ly) * (1.f - lx) * m * vy0 * vx0;
        w4[1] = (1.f - ly) * lx         * m * vy0 * vx1;
        w4[2] = ly         * (1.f - lx) * m * vy1 * vx0;
        w4[3] = ly         * lx         * m * vy1 * vx1;
        const int yc0 = min(max(y0, 0), HH - 1);
        const int yc1 = min(max(y0 + 1, 0), HH - 1);
        const int xc0 = min(max(x0, 0), WW - 1);
        const int xc1 = min(max(x0 + 1, 0), WW - 1);
        eW[e] = w4;
        eO[e] = make_uint2((unsigned)((yc0 << 7) + xc0) | ((unsigned)((yc0 << 7) + xc1) << 16),
                           (unsigned)((yc1 << 7) + xc0) | ((unsigned)((yc1 << 7) + xc1) << 16));
    }
    __syncthreads();

    const int px_l = lane & 31;
    const int hi   = lane >> 5;
    const unsigned short* __restrict__ xgb = xg + (size_t)b * 48 * HW * 8;

    f32x16 acc[3];
#pragma unroll
    for (int m = 0; m < 3; m++)
#pragma unroll
        for (int r = 0; r < 16; r++) acc[m][r] = 0.f;

    // my gather chunk for pair P is 2P + w
#define GISSUE(QQ, N0, N1, N2, N3, WN)                                        \
    {                                                                         \
        const int qn_   = min((QQ), 107);                                     \
        const int c16n_ = qn_ / 9;                                            \
        const int ktn_  = qn_ - 9 * c16n_;                                    \
        const int e_    = ((c16n_ / 3) * 9 + ktn_) * 32 + px_l;               \
        const uint2 o_  = eO[e_];                                             \
        WN = eW[e_];                                                          \
        const unsigned short* base_ = xgb + (size_t)(c16n_ * 2 + hi) * (HW * 8); \
        N0 = *reinterpret_cast<const u32x4*>(base_ + (size_t)(o_.x & 0xFFFFu) * 8); \
        N1 = *reinterpret_cast<const u32x4*>(base_ + (size_t)(o_.x >> 16) * 8);     \
        N2 = *reinterpret_cast<const u32x4*>(base_ + (size_t)(o_.y & 0xFFFFu) * 8); \
        N3 = *reinterpret_cast<const u32x4*>(base_ + (size_t)(o_.y >> 16) * 8);     \
    }

    // A frags for pair P (chunks 2P, 2P+1), m-half w: 6 b128 loads
#define AISSUE(PP, DST)                                                       \
    {                                                                         \
        const short* a0_ = wA + (size_t)min(2 * (PP),     107) * 4096 + (w * 3) * 512 + lane * 8; \
        const short* a1_ = wA + (size_t)min(2 * (PP) + 1, 107) * 4096 + (w * 3) * 512 + lane * 8; \
        DST[0] = *reinterpret_cast<const short8*>(a0_);                       \
        DST[1] = *reinterpret_cast<const short8*>(a0_ + 512);                 \
        DST[2] = *reinterpret_cast<const short8*>(a0_ + 1024);                \
        DST[3] = *reinterpret_cast<const short8*>(a1_);                       \
        DST[4] = *reinterpret_cast<const short8*>(a1_ + 512);                 \
        DST[5] = *reinterpret_cast<const short8*>(a1_ + 1024);                \
    }

#define PAIRSTEP(P, Ac, C0, C1, C2, C3, WC, An, N0, N1, N2, N3, WN)           \
    {                                                                         \
        GISSUE(2 * ((P) + 1) + w, N0, N1, N2, N3, WN);                        \
        AISSUE((P) + 1, An);                                                  \
        asm volatile("s_waitcnt vmcnt(10)" ::: "memory");                     \
        u32x4 rv_;                                                            \
        _Pragma("unroll")                                                     \
        for (int jj = 0; jj < 4; jj++) {                                      \
            f32x2 v_ = WC[0] * unpk(C0[jj]) + WC[1] * unpk(C1[jj])            \
                     + WC[2] * unpk(C2[jj]) + WC[3] * unpk(C3[jj]);           \
            __hip_bfloat162 h2_ = __float22bfloat162_rn(make_float2(v_[0], v_[1])); \
            unsigned hu_; __builtin_memcpy(&hu_, &h2_, 4);                    \
            rv_[jj] = hu_;                                                    \
        }                                                                     \
        *reinterpret_cast<u32x4*>(&bfS[(P) & 1][w][lane * 8]) = rv_;          \
        asm volatile("s_waitcnt lgkmcnt(0)" ::: "memory");                    \
        __builtin_amdgcn_s_barrier();                                         \
        __builtin_amdgcn_sched_barrier(0);                                    \
        const short8 bf0_ = *reinterpret_cast<const short8*>(&bfS[(P) & 1][0][lane * 8]); \
        const short8 bf1_ = *reinterpret_cast<const short8*>(&bfS[(P) & 1][1][lane * 8]); \
        __builtin_amdgcn_s_setprio(1);                                        \
        acc[0] = __builtin_amdgcn_mfma_f32_32x32x16_bf16(Ac[0], bf0_, acc[0], 0, 0, 0); \
        acc[1] = __builtin_amdgcn_mfma_f32_32x32x16_bf16(Ac[1], bf0_, acc[1], 0, 0, 0); \
        acc[2] = __builtin_amdgcn_mfma_f32_32x32x16_bf16(Ac[2], bf0_, acc[2], 0, 0, 0); \
        acc[0] = __builtin_amdgcn_mfma_f32_32x32x16_bf16(Ac[3], bf1_, acc[0], 0, 0, 0); \
        acc[1] = __builtin_amdgcn_mfma_f32_32x32x16_bf16(Ac[4], bf1_, acc[1], 0, 0, 0); \
        acc[2] = __builtin_amdgcn_mfma_f32_32x32x16_bf16(Ac[5], bf1_, acc[2], 0, 0, 0); \
        __builtin_amdgcn_s_setprio(0);                                        \
    }

    short8 Aa[6], Ab[6];
    u32x4 Gx0, Gx1, Gx2, Gx3, Gy0, Gy1, Gy2, Gy3;
    f32x4 wGx, wGy;

    // prologue: pair 0's G (4) + A (6) -> 10 outstanding
    GISSUE(0 + w, Gx0, Gx1, Gx2, Gx3, wGx);
    AISSUE(0, Aa);

    for (int pr = 0; pr < 54; pr += 2) {
        PAIRSTEP(pr,     Aa, Gx0, Gx1, Gx2, Gx3, wGx, Ab, Gy0, Gy1, Gy2, Gy3, wGy);
        PAIRSTEP(pr + 1, Ab, Gy0, Gy1, Gy2, Gy3, wGy, Aa, Gx0, Gx1, Gx2, Gx3, wGx);
    }
#undef PAIRSTEP
#undef AISSUE
#undef GISSUE

    const int pos_o = (i << 7) + j0 + px_l;
#pragma unroll
    for (int m = 0; m < 3; m++) {
        const int mt32 = w * 3 + m;
#pragma unroll
        for (int reg = 0; reg < 16; reg++) {
            const int o = mt32 * 32 + (reg & 3) + ((reg >> 2) << 3) + (hi << 2);
            out[((size_t)(b * CC + o) << 14) + pos_o] = acc[m][reg] + bias[o];
        }
    }
}

// ---------------------------------------------------------------------------
extern "C" void kernel_launch(void* const* d_in, const int* in_sizes, int n_in,
                              void* d_out, int out_size, void* d_ws, size_t ws_size,
                              hipStream_t stream)
{
    const float* x_vq  = (const float*)d_in[0];
    const float* x_res = (const float*)d_in[1];
    const float* w_off = (const float*)d_in[2];
    const float* b_off = (const float*)d_in[3];
    const float* w_co  = (const float*)d_in[4];
    const float* b_co  = (const float*)d_in[5];
    const float* w_dcn = (const float*)d_in[6];
    const float* b_dcn = (const float*)d_in[7];
    float* out = (float*)d_out;

    char* ws = (char*)d_ws;
    unsigned short* xg = (unsigned short*)ws;                      // 25.17 MB
    const size_t xg_sz = (size_t)BB * 48 * HW * 8 * 2;
    unsigned short* fg = (unsigned short*)(ws + xg_sz);            // 12.58 MB
    const size_t fg_sz = (size_t)BB * 24 * HW * 8 * 2;
    float* offb = (float*)(ws + xg_sz + fg_sz);                    // 14.16 MB
    const size_t offb_sz = (size_t)BB * 108 * HW * 4;
    short* wA1 = (short*)(ws + xg_sz + fg_sz + offb_sz);           // 216*4096
    short* wA2 = wA1 + (size_t)216 * 4096;                         // 108*4096
    short* wA3 = wA2 + (size_t)108 * 4096;                         // 108*4096

    // merged prep: transpose + all three packs in ONE launch
    prep_k<<<dim3(6144 + 432 + 216 + 216), 256, 0, stream>>>(
        x_vq, x_res, xg, w_off, wA1, w_co, wA2, w_dcn, wA3);

    // conv1: xg [48 grp] -> fg [24 grp bf16]
    conv_g_k<3, 24, true><<<dim3(2, HH, BB), 256, 0, stream>>>(xg, wA1, b_off, fg, 192);
    // conv2: fg [24 grp] -> offb [108 planar f32]
    conv_g_k<2, 12, false><<<dim3(2, HH, BB), 256, 0, stream>>>(fg, wA2, b_co, offb, 108);
    // fused deform-sample + einsum (producer-split)
    dcn_g_k<<<dim3(4, HH, BB), 128, 0, stream>>>(xg, offb, wA3, b_dcn, out);
}